// Round 14
// baseline (348.673 us; speedup 1.0000x reference)
//
#include <hip/hip_runtime.h>
#include <hip/hip_bf16.h>
#include <math.h>

// Problem constants
constexpr int B_ = 8, C_ = 256, H_ = 64, W_ = 64;
constexpr int N_ = H_ * W_;          // 4096
constexpr int NH_ = 8;
constexpr int CM_ = 2048;
constexpr int M_ = B_ * N_;          // 32768
constexpr float EPS_ = 1e-5f;

typedef __bf16 bf16_t;
typedef bf16_t bf16x4 __attribute__((ext_vector_type(4)));
typedef bf16_t bf16x8 __attribute__((ext_vector_type(8)));
typedef float f32x4 __attribute__((ext_vector_type(4)));
typedef float f32x16 __attribute__((ext_vector_type(16)));

__device__ inline bf16_t f2b(float f) {
    __hip_bfloat16 h = __float2bfloat16(f);
    return *reinterpret_cast<bf16_t*>(&h);
}
__device__ inline float b2f(bf16_t b) {
    unsigned short u = *reinterpret_cast<unsigned short*>(&b);
    unsigned int x = (unsigned int)u << 16;
    return *reinterpret_cast<float*>(&x);
}
__device__ inline unsigned pk2(float lo, float hi) {
    bf16_t l = f2b(lo), h = f2b(hi);
    unsigned short ls = *reinterpret_cast<unsigned short*>(&l);
    unsigned short hs = *reinterpret_cast<unsigned short*>(&h);
    return ((unsigned)hs << 16) | (unsigned)ls;
}
__device__ inline float gelu_ap(float y) {
    float u = y * (0.7978845608f + 0.0356774081f * y * y);
    float e = __expf(2.0f * u);
    return y - y * __builtin_amdgcn_rcpf(e + 1.0f);
}

#define GLOAD_LDS16(gptr, lptr)                                                     \
    __builtin_amdgcn_global_load_lds(                                               \
        (const __attribute__((address_space(1))) void*)(gptr),                      \
        (__attribute__((address_space(3))) void*)(lptr), 16, 0, 0)

// ---------------------------------------------------------------------------
// Merged prep: x [B,C,N] -> t_b [B,N,C] bf16, plus 4 weight cast+transposes.
__global__ __launch_bounds__(256)
void prep(const float* __restrict__ x, bf16_t* __restrict__ t_b,
          const float* __restrict__ Wqkv, bf16_t* __restrict__ WqkvT,
          const float* __restrict__ Wproj, bf16_t* __restrict__ WprojT,
          const float* __restrict__ Wfc1, bf16_t* __restrict__ Wfc1T,
          const float* __restrict__ Wfc2, bf16_t* __restrict__ Wfc2T) {
    __shared__ float tile[32][33];
    int id = blockIdx.x;
    int tx = threadIdx.x, ty = threadIdx.y;

    const float* src;
    bf16_t* dst;
    int K, N, k0, n0;

    if (id < 8192) {               // transpose x -> t_b (per batch b)
        int b = id >> 10, rem = id & 1023;
        int nn = (rem & 127) * 32, cc = (rem >> 7) * 32;
#pragma unroll
        for (int i = ty; i < 32; i += 8)
            tile[i][tx] = x[(size_t)b * C_ * N_ + (size_t)(cc + i) * N_ + nn + tx];
        __syncthreads();
#pragma unroll
        for (int i = ty; i < 32; i += 8)
            t_b[(size_t)b * N_ * C_ + (size_t)(nn + i) * C_ + cc + tx] = f2b(tile[tx][i]);
        return;
    } else if (id < 8384) {        // Wqkv [256,768] -> [768,256]
        int idw = id - 8192; K = C_; N = 768;
        n0 = (idw % 24) * 32; k0 = (idw / 24) * 32;
        src = Wqkv; dst = WqkvT;
    } else if (id < 8448) {        // Wproj [256,256]
        int idw = id - 8384; K = C_; N = C_;
        n0 = (idw & 7) * 32; k0 = (idw >> 3) * 32;
        src = Wproj; dst = WprojT;
    } else if (id < 8960) {        // Wfc1 [256,2048] -> [2048,256]
        int idw = id - 8448; K = C_; N = CM_;
        n0 = (idw & 63) * 32; k0 = (idw >> 6) * 32;
        src = Wfc1; dst = Wfc1T;
    } else {                       // Wfc2 [2048,256] -> [256,2048]
        int idw = id - 8960; K = CM_; N = C_;
        n0 = (idw & 7) * 32; k0 = (idw >> 3) * 32;
        src = Wfc2; dst = Wfc2T;
    }
#pragma unroll
    for (int i = ty; i < 32; i += 8)
        tile[i][tx] = src[(size_t)(k0 + i) * N + n0 + tx];
    __syncthreads();
#pragma unroll
    for (int i = ty; i < 32; i += 8)
        dst[(size_t)(n0 + i) * K + k0 + tx] = f2b(tile[tx][i]);
}

// ---------------------------------------------------------------------------
// Swapped-operand bf16 MFMA GEMM (qkv / proj): out[m,ch] = Act[m,:].Wt[ch,:]+bias.
// 128x128 tile, BK=64, single-buffer 32KB LDS, 4 blocks/CU. EPI 4 / EPI 1.
template <int EPI>
__global__ __launch_bounds__(256, 4)
void gemm_swp(const bf16_t* __restrict__ Wt, const bf16_t* __restrict__ Act,
              const float* __restrict__ bias, bf16_t* __restrict__ Cb,
              int M, int N, int K,
              const bf16_t* __restrict__ tres_b,
              const float* __restrict__ g, const float* __restrict__ bb,
              const float* __restrict__ mm, const float* __restrict__ vv,
              const float* __restrict__ alpha) {
    __shared__ bf16x8 ldsv[2048];          // 32 KB: W [0,1024), Act [1024,2048)
    char* lds = (char*)ldsv;

    int tid  = threadIdx.x;
    int lane = tid & 63;
    int w    = tid >> 6;
    int wi   = w >> 1, wj = w & 1;

    int nwg = gridDim.x * gridDim.y;
    int bid = blockIdx.y * gridDim.x + blockIdx.x;
    int swz = (bid & 7) * (nwg >> 3) + (bid >> 3);
    int bx = swz % gridDim.x, by = swz / gridDim.x;
    int bch = bx * 128, bm = by * 128;

    int rowl = lane & 15, kq = lane >> 4;

    f32x4 acc[4][4] = {};

    for (int k0 = 0; k0 < K; k0 += 64) {
#pragma unroll
        for (int j = 0; j < 4; ++j) {
            int jj = w * 4 + j;
            int msub = jj >> 1, kh = jj & 1;
            const bf16_t* gw = Wt + ((size_t)(bch + msub * 16 + rowl) * K + k0 + kh * 32 + kq * 8);
            GLOAD_LDS16(gw, lds + jj * 1024);
            const bf16_t* ga = Act + ((size_t)(bm + msub * 16 + rowl) * K + k0 + kh * 32 + kq * 8);
            GLOAD_LDS16(ga, lds + 16384 + jj * 1024);
        }
        __syncthreads();
#pragma unroll
        for (int ks = 0; ks < 2; ++ks) {
            bf16x8 wf[4], af[4];
#pragma unroll
            for (int i = 0; i < 4; ++i) wf[i] = ldsv[((wi * 4 + i) * 2 + ks) * 64 + lane];
#pragma unroll
            for (int j = 0; j < 4; ++j) af[j] = ldsv[1024 + ((wj * 4 + j) * 2 + ks) * 64 + lane];
#pragma unroll
            for (int i = 0; i < 4; ++i)
#pragma unroll
                for (int j = 0; j < 4; ++j)
                    acc[i][j] = __builtin_amdgcn_mfma_f32_16x16x32_bf16(wf[i], af[j], acc[i][j], 0, 0, 0);
        }
        __syncthreads();
    }

    float alpha_v = (EPI == 1) ? alpha[0] : 0.f;
#pragma unroll
    for (int i = 0; i < 4; ++i) {
        int ch = bch + wi * 64 + i * 16 + (lane >> 4) * 4;
        f32x4 b4 = *(const f32x4*)(bias + ch);
        f32x4 rs4, B4, m4;
        if (EPI == 1) {
            f32x4 g4 = *(const f32x4*)(g + ch);
            f32x4 v4 = *(const f32x4*)(vv + ch);
            B4 = *(const f32x4*)(bb + ch);
            m4 = *(const f32x4*)(mm + ch);
#pragma unroll
            for (int r = 0; r < 4; ++r) rs4[r] = rsqrtf(v4[r] + EPS_) * g4[r];
        }
#pragma unroll
        for (int j = 0; j < 4; ++j) {
            int m = bm + wj * 64 + j * 16 + (lane & 15);
            f32x4 a = acc[i][j];
            bf16_t ob[4];
            if (EPI == 4) {
#pragma unroll
                for (int r = 0; r < 4; ++r) ob[r] = f2b(a[r] + b4[r]);
            } else {  // EPI 1
                bf16x4 t4 = *(const bf16x4*)(tres_b + (size_t)m * N + ch);
#pragma unroll
                for (int r = 0; r < 4; ++r) {
                    float z = b2f(t4[r]) + a[r] + b4[r];
                    ob[r] = f2b((z - m4[r]) * rs4[r] + B4[r] + alpha_v * z);
                }
            }
            *(bf16x4*)(Cb + (size_t)m * N + ch) = *(bf16x4*)ob;
        }
    }
}

// ---------------------------------------------------------------------------
// Fused FFN v8: out = repbn2(t + gelu(t@W1+b1)@W2 + b2) -> [B,C,N] f32.
// Shell identical to v4 (512 thr, BM=64, LDS 64KB = A 32K + 2x16K hidden dbuf,
// 1 barrier/chunk, fc2 on 16x16x32). fc1 upgraded to 32x32x16 (2x FLOP per
// ds_read_b128; fc1 LDS reads halved), spill-proofed vs v5: ONE f32x16 chain,
// W1 streamed in 4 scoped groups of 4 frags. Mapping verified in v5 (passed).
__global__ __launch_bounds__(512, 4)
void ffn_fused(const bf16_t* __restrict__ Act, const bf16_t* __restrict__ W1t,
               const bf16_t* __restrict__ W2t,
               const float* __restrict__ bfc1, const float* __restrict__ bfc2,
               const float* __restrict__ g, const float* __restrict__ bb,
               const float* __restrict__ mm, const float* __restrict__ vv,
               const float* __restrict__ alpha, float* __restrict__ out) {
    __shared__ char lds[65536];
    bf16x8* ldsA = (bf16x8*)lds;     // A panel: 32 slots (mh 2 x ksl 16), 32x32x16 B-frag layout

    const int tid = threadIdx.x;
    const int lane = tid & 63;
    const int w = tid >> 6;          // 0..7
    const int l15 = lane & 15;
    const int l31 = lane & 31;
    const int h5 = lane >> 5;        // 0..1
    const int kq = lane >> 4;        // 0..3
    const int m0 = blockIdx.x * 64;

    // ---- stage A panel 64x256: slot jj = mh*16 + ksl;
    // lane l -> Act[m0 + mh*32 + (l&31)][ksl*16 + (l>>5)*8 .. +8]
#pragma unroll
    for (int j = 0; j < 4; ++j) {
        int jj = w * 4 + j;
        int mh_ = jj >> 4, ksl = jj & 15;
        const bf16_t* src = Act + (size_t)(m0 + mh_ * 32 + l31) * 256 + ksl * 16 + h5 * 8;
        GLOAD_LDS16(src, lds + jj * 1024);
    }
    __syncthreads();

    f32x4 acc2[2][4] = {};

    const int hg = w >> 1;                   // fc1 h-group (32 rows), = fc2 ks2 slice
    const int mh = w & 1;                    // fc1 m-half
    const int mblkw = mh * 2 + ((l31 >> 4) & 1);
    const int chb = w * 32;                  // fc2 ch-base

    for (int c = 0; c < 16; ++c) {
        // ---- fc1: 32h x 32m per wave, 32x32x16 MFMA, single acc chain,
        //      W1 streamed in 4 groups of 4 frags (16 VGPR live)
        const bf16_t* w1p = W1t + (size_t)(c * 128 + hg * 32 + l31) * 256 + h5 * 8;
        f32x16 acc1 = (f32x16)0.f;
#pragma unroll
        for (int grp = 0; grp < 4; ++grp) {
            bf16x8 wl[4];
#pragma unroll
            for (int t = 0; t < 4; ++t)
                wl[t] = *(const bf16x8*)(w1p + (grp * 4 + t) * 16);
#pragma unroll
            for (int t = 0; t < 4; ++t)
                acc1 = __builtin_amdgcn_mfma_f32_32x32x16_bf16(
                    wl[t], ldsA[(mh * 16 + grp * 4 + t) * 64 + lane], acc1, 0, 0, 0);
        }

        // ---- W2 chunk c -> regs (consumed after barrier; covered by gelu+drain)
        bf16x8 w2f[2][4];
#pragma unroll
        for (int cf = 0; cf < 2; ++cf)
#pragma unroll
            for (int ks2 = 0; ks2 < 4; ++ks2)
                w2f[cf][ks2] = *(const bf16x8*)(W2t + (size_t)(chb + cf * 16 + l15) * 2048 + c * 128 + ks2 * 32 + kq * 8);

        // ---- bias + gelu + pack -> hidden buf[c&1]
        // acc1[4q+j] = hidden[h = hg*32 + 8q + 4*h5 + j][m = mh*32 + l31]
        char* hbase = lds + 32768 + (c & 1) * 16384;
#pragma unroll
        for (int q = 0; q < 4; ++q) {
            f32x4 b1 = *(const f32x4*)(bfc1 + c * 128 + hg * 32 + 8 * q + 4 * h5);
            uint2 u2;
            u2.x = pk2(gelu_ap(acc1[4 * q + 0] + b1[0]), gelu_ap(acc1[4 * q + 1] + b1[1]));
            u2.y = pk2(gelu_ap(acc1[4 * q + 2] + b1[2]), gelu_ap(acc1[4 * q + 3] + b1[3]));
            *(uint2*)(hbase + (size_t)(((mblkw * 4 + hg) * 64) + (l15 + (q << 4))) * 16 + h5 * 8) = u2;
        }
        __syncthreads();   // single barrier per chunk (dbuf removes WAR hazard)

        // ---- fc2 partial: 64m x 32ch per wave (16x16x32), unchanged
        bf16x8* ldsH = (bf16x8*)(lds + 32768 + (c & 1) * 16384);
#pragma unroll
        for (int mblk = 0; mblk < 4; ++mblk)
#pragma unroll
            for (int ks2 = 0; ks2 < 4; ++ks2) {
                bf16x8 hf = ldsH[(mblk * 4 + ks2) * 64 + lane];
                acc2[0][mblk] = __builtin_amdgcn_mfma_f32_16x16x32_bf16(hf, w2f[0][ks2], acc2[0][mblk], 0, 0, 0);
                acc2[1][mblk] = __builtin_amdgcn_mfma_f32_16x16x32_bf16(hf, w2f[1][ks2], acc2[1][mblk], 0, 0, 0);
            }
    }

    // ---- epilogue: repbn2 + transpose to [B,C,N], native f32x4 stores
    float alpha_v = alpha[0];
#pragma unroll
    for (int cf = 0; cf < 2; ++cf) {
        int ch = chb + cf * 16 + l15;
        float b2v = bfc2[ch];
        float rs = rsqrtf(vv[ch] + EPS_) * g[ch];
        float bbv = bb[ch], mv = mm[ch];
#pragma unroll
        for (int mblk = 0; mblk < 4; ++mblk) {
            int mbase = m0 + mblk * 16 + kq * 4;
            f32x4 o4;
#pragma unroll
            for (int r = 0; r < 4; ++r) {
                float z = b2f(Act[(size_t)(mbase + r) * 256 + ch]) + acc2[cf][mblk][r] + b2v;
                o4[r] = (z - mv) * rs + bbv + alpha_v * z;
            }
            int bi = mbase >> 12, ni = mbase & (N_ - 1);
            *(f32x4*)(out + ((size_t)bi * C_ + ch) * N_ + ni) = o4;
        }
    }
}

// ---------------------------------------------------------------------------
// ctx partials: ctxp[seg][b*NH+h][d][e] = sum_{n in seg} relu(k[n,d]) * v[n,e]
__global__ void ctx_partial(const bf16_t* __restrict__ qkv, float* __restrict__ ctxp) {
    __shared__ float kb[64][40];
    __shared__ float vb[64][40];
    int seg = blockIdx.x;
    int bh  = blockIdx.y;
    int b = bh >> 3, h = bh & 7;
    int tid = threadIdx.x;
    int d  = tid >> 3;
    int e0 = (tid & 7) * 4;
    int lrow = tid >> 2, lcol = (tid & 3) * 8;
    float acc[4] = {0.f, 0.f, 0.f, 0.f};
    const size_t base = (size_t)b * N_ * 768 + h * 32;
    for (int n0 = seg * 512; n0 < seg * 512 + 512; n0 += 64) {
        size_t ra = base + (size_t)(n0 + lrow) * 768 + lcol;
        bf16x8 kv8 = *(const bf16x8*)(qkv + ra + 256);
        bf16x8 vv8 = *(const bf16x8*)(qkv + ra + 512);
#pragma unroll
        for (int j = 0; j < 8; ++j) {
            kb[lrow][lcol + j] = b2f(kv8[j]);
            vb[lrow][lcol + j] = b2f(vv8[j]);
        }
        __syncthreads();
#pragma unroll
        for (int nl = 0; nl < 64; ++nl) {
            float kv = fmaxf(kb[nl][d], 0.f);
#pragma unroll
            for (int j = 0; j < 4; ++j)
                acc[j] = fmaf(kv, vb[nl][e0 + j], acc[j]);
        }
        __syncthreads();
    }
    float* o = ctxp + ((size_t)seg * 64 + bh) * 1024 + d * 32 + e0;
#pragma unroll
    for (int j = 0; j < 4; ++j) o[j] = acc[j];
}

// ---------------------------------------------------------------------------
// attn_out with fused ctx reduction: cs = sum_seg ctxp[seg][bh]
__global__ void attn_out(const bf16_t* __restrict__ qkv, const float* __restrict__ ctxp,
                         bf16_t* __restrict__ img) {
    __shared__ float qb[64][33];
    __shared__ float cs[32][32];
    int n0 = blockIdx.x * 64;
    int bh = blockIdx.y;
    int b = bh >> 3, h = bh & 7;
    int tid = threadIdx.x;
    const float scale = 0.17677669529663687f;
    {
        f32x4 vv = (f32x4)0.f;
#pragma unroll
        for (int seg = 0; seg < 8; ++seg) {
            f32x4 t = ((const f32x4*)(ctxp + ((size_t)seg * 64 + bh) * 1024))[tid];
            vv = vv + t;
        }
        ((f32x4*)&cs[0][0])[tid] = vv;
    }
    const size_t base = (size_t)b * N_ * 768 + h * 32;
    int lrow = tid >> 2, lcol = (tid & 3) * 8;
    {
        bf16x8 q8 = *(const bf16x8*)(qkv + base + (size_t)(n0 + lrow) * 768 + lcol);
#pragma unroll
        for (int j = 0; j < 8; ++j)
            qb[lrow][lcol + j] = fmaxf(b2f(q8[j]), 0.f) * scale;
    }
    __syncthreads();
    int nl = tid & 63, ebase = tid >> 6;
    bf16_t* outp = img + ((size_t)b * C_ + h * 32) * N_ + n0 + nl;
#pragma unroll
    for (int p = 0; p < 8; ++p) {
        int e = ebase + p * 4;
        float s = 0.f;
#pragma unroll
        for (int dd = 0; dd < 32; ++dd)
            s = fmaf(qb[nl][dd], cs[dd][e], s);
        outp[(size_t)e * N_] = f2b(s);
    }
}

// ---------------------------------------------------------------------------
// Fused depthwise 3x3 conv + transpose: img [B,C,N] bf16 -> convT [B,N,C] bf16.
__global__ __launch_bounds__(256)
void dwconvT(const bf16_t* __restrict__ img, const float* __restrict__ w,
             const float* __restrict__ bias, bf16_t* __restrict__ outb) {
    __shared__ float spf[3][32][66];
    __shared__ float otile[64][33];
    int id = blockIdx.x;               // b*512 + y*8 + cg
    int cg = id & 7, y = (id >> 3) & 63, b = id >> 9;
    int tid = threadIdx.x;
    int c_l = tid >> 3, xg = tid & 7;
    int c = cg * 32 + c_l;
    const bf16_t* ip = img + (size_t)(b * C_ + c) * N_;
#pragma unroll
    for (int dy = 0; dy < 3; ++dy) {
        int yy = y + dy - 1;
        if (yy < 0 || yy > 63) {
#pragma unroll
            for (int j = 0; j < 8; ++j) spf[dy][c_l][xg * 8 + j] = 0.f;
        } else {
            bf16x8 v8 = *(const bf16x8*)(ip + yy * 64 + xg * 8);
#pragma unroll
            for (int j = 0; j < 8; ++j) spf[dy][c_l][xg * 8 + j] = b2f(v8[j]);
        }
    }
    float wv[9];
#pragma unroll
    for (int j = 0; j < 9; ++j) wv[j] = w[c * 9 + j];
    float bv = bias[c];
    __syncthreads();

    float o[8];
#pragma unroll
    for (int i = 0; i < 8; ++i) o[i] = bv;
#pragma unroll
    for (int dy = 0; dy < 3; ++dy)
#pragma unroll
        for (int dx = -1; dx <= 1; ++dx) {
            float wgt = wv[dy * 3 + dx + 1];
#pragma unroll
            for (int i = 0; i < 8; ++i) {
                int xx = xg * 8 + i + dx;
                float val = (xx < 0 || xx > 63) ? 0.f : spf[dy][c_l][xx];
                o[i] = fmaf(wgt, val, o[i]);
            }
        }
#pragma unroll
    for (int i = 0; i < 8; ++i) otile[xg * 8 + i][c_l] = o[i];
    __syncthreads();

    int x_o = tid >> 2, cq = tid & 3;
    bf16_t ob[8];
#pragma unroll
    for (int j = 0; j < 8; ++j) ob[j] = f2b(otile[x_o][cq * 8 + j]);
    *(bf16x8*)(outb + ((size_t)b * N_ + y * 64 + x_o) * 256 + cg * 32 + cq * 8) = *(bf16x8*)&ob[0];
}

// ---------------------------------------------------------------------------
extern "C" void kernel_launch(void* const* d_in, const int* in_sizes, int n_in,
                              void* d_out, int out_size, void* d_ws, size_t ws_size,
                              hipStream_t stream) {
    const float* x     = (const float*)d_in[0];
    const float* Wqkv  = (const float*)d_in[1];
    const float* bqkv  = (const float*)d_in[2];
    const float* dw_w  = (const float*)d_in[3];
    const float* dw_b  = (const float*)d_in[4];
    const float* Wproj = (const float*)d_in[5];
    const float* bproj = (const float*)d_in[6];
    const float* bn1_g = (const float*)d_in[7];
    const float* bn1_b = (const float*)d_in[8];
    const float* bn1_m = (const float*)d_in[9];
    const float* bn1_v = (const float*)d_in[10];
    const float* alpha1= (const float*)d_in[11];
    const float* Wfc1  = (const float*)d_in[12];
    const float* bfc1  = (const float*)d_in[13];
    const float* Wfc2  = (const float*)d_in[14];
    const float* bfc2  = (const float*)d_in[15];
    const float* bn2_g = (const float*)d_in[16];
    const float* bn2_b = (const float*)d_in[17];
    const float* bn2_m = (const float*)d_in[18];
    const float* bn2_v = (const float*)d_in[19];
    const float* alpha2= (const float*)d_in[20];
    float* out = (float*)d_out;

    char* ws = (char*)d_ws;
    bf16_t* t_b2    = (bf16_t*)(ws);
    bf16_t* WqkvT   = (bf16_t*)(ws + 16777216);
    bf16_t* WprojT  = (bf16_t*)(ws + 17170432);
    bf16_t* Wfc1T   = (bf16_t*)(ws + 17301504);
    bf16_t* Wfc2T   = (bf16_t*)(ws + 18350080);
    float*  ctxp    = (float*)(ws + 19398656);
    bf16_t* t_b     = (bf16_t*)(ws + 21757952);
    bf16_t* qkv_b   = (bf16_t*)(ws + 38535168);
    bf16_t* img_b   = (bf16_t*)(ws + 88866816);
    bf16_t* convT_b = (bf16_t*)(ws + 122421248);

    // ph1: merged prep (transpose x + all 4 weight casts)
    prep<<<9472, dim3(32, 8), 0, stream>>>(x, t_b, Wqkv, WqkvT, Wproj, WprojT,
                                           Wfc1, Wfc1T, Wfc2, Wfc2T);

    // ph2: qkv_b = bf16(t @ Wqkv + bqkv)
    gemm_swp<4><<<dim3(768 / 128, M_ / 128), 256, 0, stream>>>(
        WqkvT, t_b, bqkv, qkv_b, M_, 768, C_,
        nullptr, nullptr, nullptr, nullptr, nullptr, nullptr);

    // ph3: ctx partials (reduction folded into attn_out)
    ctx_partial<<<dim3(8, B_ * NH_), 256, 0, stream>>>(qkv_b, ctxp);

    // ph4: img_b = (relu(q)*scale) @ ctx   [B,C,N] bf16
    attn_out<<<dim3(N_ / 64, B_ * NH_), 256, 0, stream>>>(qkv_b, ctxp, img_b);

    // ph5: fused depthwise conv + transpose -> convT_b [B,N,C]
    dwconvT<<<B_ * 64 * 8, 256, 0, stream>>>(img_b, dw_w, dw_b, convT_b);

    // ph6: t_b2 = repbn1(t_b + convT @ Wproj + bproj)
    gemm_swp<1><<<dim3(C_ / 128, M_ / 128), 256, 0, stream>>>(
        WprojT, convT_b, bproj, t_b2, M_, C_, C_,
        t_b, bn1_g, bn1_b, bn1_m, bn1_v, alpha1);

    // ph7: fused FFN v8 (32x32x16 fc1, spill-proofed; fc1 LDS reads halved)
    ffn_fused<<<M_ / 64, 512, 0, stream>>>(
        t_b2, Wfc1T, Wfc2T, bfc1, bfc2,
        bn2_g, bn2_b, bn2_m, bn2_v, alpha2, out);
}

// Round 15
// 286.509 us; speedup vs baseline: 1.2170x; 1.2170x over previous
//
#include <hip/hip_runtime.h>
#include <hip/hip_bf16.h>
#include <math.h>

// Problem constants
constexpr int B_ = 8, C_ = 256, H_ = 64, W_ = 64;
constexpr int N_ = H_ * W_;          // 4096
constexpr int NH_ = 8;
constexpr int CM_ = 2048;
constexpr int M_ = B_ * N_;          // 32768
constexpr float EPS_ = 1e-5f;

typedef __bf16 bf16_t;
typedef bf16_t bf16x4 __attribute__((ext_vector_type(4)));
typedef bf16_t bf16x8 __attribute__((ext_vector_type(8)));
typedef float f32x4 __attribute__((ext_vector_type(4)));

__device__ inline bf16_t f2b(float f) {
    __hip_bfloat16 h = __float2bfloat16(f);
    return *reinterpret_cast<bf16_t*>(&h);
}
__device__ inline float b2f(bf16_t b) {
    unsigned short u = *reinterpret_cast<unsigned short*>(&b);
    unsigned int x = (unsigned int)u << 16;
    return *reinterpret_cast<float*>(&x);
}
__device__ inline unsigned pk2(float lo, float hi) {
    bf16_t l = f2b(lo), h = f2b(hi);
    unsigned short ls = *reinterpret_cast<unsigned short*>(&l);
    unsigned short hs = *reinterpret_cast<unsigned short*>(&h);
    return ((unsigned)hs << 16) | (unsigned)ls;
}
__device__ inline float gelu_ap(float y) {
    float u = y * (0.7978845608f + 0.0356774081f * y * y);
    float e = __expf(2.0f * u);
    return y - y * __builtin_amdgcn_rcpf(e + 1.0f);
}

#define GLOAD_LDS16(gptr, lptr)                                                     \
    __builtin_amdgcn_global_load_lds(                                               \
        (const __attribute__((address_space(1))) void*)(gptr),                      \
        (__attribute__((address_space(3))) void*)(lptr), 16, 0, 0)

// ---------------------------------------------------------------------------
// Merged prep: x [B,C,N] -> t_b [B,N,C] bf16, plus 4 weight cast+transposes.
__global__ __launch_bounds__(256)
void prep(const float* __restrict__ x, bf16_t* __restrict__ t_b,
          const float* __restrict__ Wqkv, bf16_t* __restrict__ WqkvT,
          const float* __restrict__ Wproj, bf16_t* __restrict__ WprojT,
          const float* __restrict__ Wfc1, bf16_t* __restrict__ Wfc1T,
          const float* __restrict__ Wfc2, bf16_t* __restrict__ Wfc2T) {
    __shared__ float tile[32][33];
    int id = blockIdx.x;
    int tx = threadIdx.x, ty = threadIdx.y;

    const float* src;
    bf16_t* dst;
    int K, N, k0, n0;

    if (id < 8192) {               // transpose x -> t_b (per batch b)
        int b = id >> 10, rem = id & 1023;
        int nn = (rem & 127) * 32, cc = (rem >> 7) * 32;
#pragma unroll
        for (int i = ty; i < 32; i += 8)
            tile[i][tx] = x[(size_t)b * C_ * N_ + (size_t)(cc + i) * N_ + nn + tx];
        __syncthreads();
#pragma unroll
        for (int i = ty; i < 32; i += 8)
            t_b[(size_t)b * N_ * C_ + (size_t)(nn + i) * C_ + cc + tx] = f2b(tile[tx][i]);
        return;
    } else if (id < 8384) {        // Wqkv [256,768] -> [768,256]
        int idw = id - 8192; K = C_; N = 768;
        n0 = (idw % 24) * 32; k0 = (idw / 24) * 32;
        src = Wqkv; dst = WqkvT;
    } else if (id < 8448) {        // Wproj [256,256]
        int idw = id - 8384; K = C_; N = C_;
        n0 = (idw & 7) * 32; k0 = (idw >> 3) * 32;
        src = Wproj; dst = WprojT;
    } else if (id < 8960) {        // Wfc1 [256,2048] -> [2048,256]
        int idw = id - 8448; K = C_; N = CM_;
        n0 = (idw & 63) * 32; k0 = (idw >> 6) * 32;
        src = Wfc1; dst = Wfc1T;
    } else {                       // Wfc2 [2048,256] -> [256,2048]
        int idw = id - 8960; K = CM_; N = C_;
        n0 = (idw & 7) * 32; k0 = (idw >> 3) * 32;
        src = Wfc2; dst = Wfc2T;
    }
#pragma unroll
    for (int i = ty; i < 32; i += 8)
        tile[i][tx] = src[(size_t)(k0 + i) * N + n0 + tx];
    __syncthreads();
#pragma unroll
    for (int i = ty; i < 32; i += 8)
        dst[(size_t)(n0 + i) * K + k0 + tx] = f2b(tile[tx][i]);
}

// ---------------------------------------------------------------------------
// Swapped-operand bf16 MFMA GEMM (qkv / proj): out[m,ch] = Act[m,:].Wt[ch,:]+bias.
// 128x128 tile, BK=64, single-buffer 32KB LDS, 4 blocks/CU. EPI 4 / EPI 1.
template <int EPI>
__global__ __launch_bounds__(256, 4)
void gemm_swp(const bf16_t* __restrict__ Wt, const bf16_t* __restrict__ Act,
              const float* __restrict__ bias, bf16_t* __restrict__ Cb,
              int M, int N, int K,
              const bf16_t* __restrict__ tres_b,
              const float* __restrict__ g, const float* __restrict__ bb,
              const float* __restrict__ mm, const float* __restrict__ vv,
              const float* __restrict__ alpha) {
    __shared__ bf16x8 ldsv[2048];          // 32 KB: W [0,1024), Act [1024,2048)
    char* lds = (char*)ldsv;

    int tid  = threadIdx.x;
    int lane = tid & 63;
    int w    = tid >> 6;
    int wi   = w >> 1, wj = w & 1;

    int nwg = gridDim.x * gridDim.y;
    int bid = blockIdx.y * gridDim.x + blockIdx.x;
    int swz = (bid & 7) * (nwg >> 3) + (bid >> 3);
    int bx = swz % gridDim.x, by = swz / gridDim.x;
    int bch = bx * 128, bm = by * 128;

    int rowl = lane & 15, kq = lane >> 4;

    f32x4 acc[4][4] = {};

    for (int k0 = 0; k0 < K; k0 += 64) {
#pragma unroll
        for (int j = 0; j < 4; ++j) {
            int jj = w * 4 + j;
            int msub = jj >> 1, kh = jj & 1;
            const bf16_t* gw = Wt + ((size_t)(bch + msub * 16 + rowl) * K + k0 + kh * 32 + kq * 8);
            GLOAD_LDS16(gw, lds + jj * 1024);
            const bf16_t* ga = Act + ((size_t)(bm + msub * 16 + rowl) * K + k0 + kh * 32 + kq * 8);
            GLOAD_LDS16(ga, lds + 16384 + jj * 1024);
        }
        __syncthreads();
#pragma unroll
        for (int ks = 0; ks < 2; ++ks) {
            bf16x8 wf[4], af[4];
#pragma unroll
            for (int i = 0; i < 4; ++i) wf[i] = ldsv[((wi * 4 + i) * 2 + ks) * 64 + lane];
#pragma unroll
            for (int j = 0; j < 4; ++j) af[j] = ldsv[1024 + ((wj * 4 + j) * 2 + ks) * 64 + lane];
#pragma unroll
            for (int i = 0; i < 4; ++i)
#pragma unroll
                for (int j = 0; j < 4; ++j)
                    acc[i][j] = __builtin_amdgcn_mfma_f32_16x16x32_bf16(wf[i], af[j], acc[i][j], 0, 0, 0);
        }
        __syncthreads();
    }

    float alpha_v = (EPI == 1) ? alpha[0] : 0.f;
#pragma unroll
    for (int i = 0; i < 4; ++i) {
        int ch = bch + wi * 64 + i * 16 + (lane >> 4) * 4;
        f32x4 b4 = *(const f32x4*)(bias + ch);
        f32x4 rs4, B4, m4;
        if (EPI == 1) {
            f32x4 g4 = *(const f32x4*)(g + ch);
            f32x4 v4 = *(const f32x4*)(vv + ch);
            B4 = *(const f32x4*)(bb + ch);
            m4 = *(const f32x4*)(mm + ch);
#pragma unroll
            for (int r = 0; r < 4; ++r) rs4[r] = rsqrtf(v4[r] + EPS_) * g4[r];
        }
#pragma unroll
        for (int j = 0; j < 4; ++j) {
            int m = bm + wj * 64 + j * 16 + (lane & 15);
            f32x4 a = acc[i][j];
            bf16_t ob[4];
            if (EPI == 4) {
#pragma unroll
                for (int r = 0; r < 4; ++r) ob[r] = f2b(a[r] + b4[r]);
            } else {  // EPI 1
                bf16x4 t4 = *(const bf16x4*)(tres_b + (size_t)m * N + ch);
#pragma unroll
                for (int r = 0; r < 4; ++r) {
                    float z = b2f(t4[r]) + a[r] + b4[r];
                    ob[r] = f2b((z - m4[r]) * rs4[r] + B4[r] + alpha_v * z);
                }
            }
            *(bf16x4*)(Cb + (size_t)m * N + ch) = *(bf16x4*)ob;
        }
    }
}

// ---------------------------------------------------------------------------
// Fused FFN v4 (verified 145us): out = repbn2(t + gelu(t@W1+b1)@W2+b2).
// 64-row m-panel, 512 threads, LDS 64KB (A 32K + 2x16K hidden dbuf).
// ONE barrier per chunk; w1f reload after last use; w2f issued pre-barrier.
__global__ __launch_bounds__(512, 4)
void ffn_fused(const bf16_t* __restrict__ Act, const bf16_t* __restrict__ W1t,
               const bf16_t* __restrict__ W2t,
               const float* __restrict__ bfc1, const float* __restrict__ bfc2,
               const float* __restrict__ g, const float* __restrict__ bb,
               const float* __restrict__ mm, const float* __restrict__ vv,
               const float* __restrict__ alpha, float* __restrict__ out) {
    __shared__ char lds[65536];
    bf16x8* ldsA = (bf16x8*)lds;            // A panel: 32 frags x 64 lanes

    const int tid = threadIdx.x;
    const int lane = tid & 63;
    const int w = tid >> 6;          // 0..7
    const int l15 = lane & 15;
    const int kq = lane >> 4;        // 0..3
    const int m0 = blockIdx.x * 64;

    // ---- stage A panel 64x256 (frag-linear)
#pragma unroll
    for (int j = 0; j < 4; ++j) {
        int jj = w * 4 + j;
        int mblk = jj >> 3, ks = jj & 7;
        const bf16_t* src = Act + (size_t)(m0 + mblk * 16 + l15) * 256 + ks * 32 + kq * 8;
        GLOAD_LDS16(src, lds + jj * 1024);
    }
    __syncthreads();

    f32x4 acc2[2][4] = {};

    const int hrow = w * 16 + l15;                         // W1 row within chunk
    const int ks2w = w >> 1;                               // hidden write frag ks2
    const int lane2 = l15 + (((2 * w + (kq >> 1)) & 3) << 4);
    const int hwoff = (kq & 1) << 3;                       // byte 0 / 8
    const int chb = w * 32;

    // ---- prologue: W1 chunk 0 -> regs
    bf16x8 w1f[8];
#pragma unroll
    for (int ks = 0; ks < 8; ++ks)
        w1f[ks] = *(const bf16x8*)(W1t + (size_t)hrow * 256 + ks * 32 + kq * 8);

    for (int c = 0; c < 16; ++c) {
        // ---- fc1: 16h x 64m per wave (swapped)
        f32x4 acc1[4] = {};
#pragma unroll
        for (int ks = 0; ks < 8; ++ks)
#pragma unroll
            for (int mblk = 0; mblk < 4; ++mblk)
                acc1[mblk] = __builtin_amdgcn_mfma_f32_16x16x32_bf16(
                    w1f[ks], ldsA[(mblk * 8 + ks) * 64 + lane], acc1[mblk], 0, 0, 0);

        // ---- reload W1 for next chunk into the now-dead regs
        if (c + 1 < 16) {
#pragma unroll
            for (int ks = 0; ks < 8; ++ks)
                w1f[ks] = *(const bf16x8*)(W1t + (size_t)((c + 1) * 128 + hrow) * 256 + ks * 32 + kq * 8);
        }
        // ---- W2 chunk c -> regs (used after the barrier; covered by gelu+drain)
        bf16x8 w2f[2][4];
#pragma unroll
        for (int cf = 0; cf < 2; ++cf)
#pragma unroll
            for (int ks2 = 0; ks2 < 4; ++ks2)
                w2f[cf][ks2] = *(const bf16x8*)(W2t + (size_t)(chb + cf * 16 + l15) * 2048 + c * 128 + ks2 * 32 + kq * 8);

        // ---- bias + gelu + pack -> hidden buf[c&1] (b64 writes)
        f32x4 b1 = *(const f32x4*)(bfc1 + c * 128 + w * 16 + kq * 4);
        char* hbase = lds + 32768 + (c & 1) * 16384;
#pragma unroll
        for (int mblk = 0; mblk < 4; ++mblk) {
            uint2 u2;
            u2.x = pk2(gelu_ap(acc1[mblk][0] + b1[0]), gelu_ap(acc1[mblk][1] + b1[1]));
            u2.y = pk2(gelu_ap(acc1[mblk][2] + b1[2]), gelu_ap(acc1[mblk][3] + b1[3]));
            *(uint2*)(hbase + (size_t)((mblk * 4 + ks2w) * 64 + lane2) * 16 + hwoff) = u2;
        }
        __syncthreads();   // single barrier per chunk (dbuf removes WAR hazard)

        // ---- fc2 partial: 64m x 32ch per wave
        bf16x8* ldsH = (bf16x8*)(lds + 32768 + (c & 1) * 16384);
#pragma unroll
        for (int mblk = 0; mblk < 4; ++mblk)
#pragma unroll
            for (int ks2 = 0; ks2 < 4; ++ks2) {
                bf16x8 hf = ldsH[(mblk * 4 + ks2) * 64 + lane];
                acc2[0][mblk] = __builtin_amdgcn_mfma_f32_16x16x32_bf16(hf, w2f[0][ks2], acc2[0][mblk], 0, 0, 0);
                acc2[1][mblk] = __builtin_amdgcn_mfma_f32_16x16x32_bf16(hf, w2f[1][ks2], acc2[1][mblk], 0, 0, 0);
            }
    }

    // ---- epilogue: repbn2 + transpose to [B,C,N], native f32x4 stores
    float alpha_v = alpha[0];
#pragma unroll
    for (int cf = 0; cf < 2; ++cf) {
        int ch = chb + cf * 16 + l15;
        float b2v = bfc2[ch];
        float rs = rsqrtf(vv[ch] + EPS_) * g[ch];
        float bbv = bb[ch], mv = mm[ch];
#pragma unroll
        for (int mblk = 0; mblk < 4; ++mblk) {
            int mbase = m0 + mblk * 16 + kq * 4;
            f32x4 o4;
#pragma unroll
            for (int r = 0; r < 4; ++r) {
                float z = b2f(Act[(size_t)(mbase + r) * 256 + ch]) + acc2[cf][mblk][r] + b2v;
                o4[r] = (z - mv) * rs + bbv + alpha_v * z;
            }
            int bi = mbase >> 12, ni = mbase & (N_ - 1);
            *(f32x4*)(out + ((size_t)bi * C_ + ch) * N_ + ni) = o4;
        }
    }
}

// ---------------------------------------------------------------------------
// ctx partials: ctxp[seg][b*NH+h][d][e] = sum_{n in seg} relu(k[n,d]) * v[n,e]
__global__ void ctx_partial(const bf16_t* __restrict__ qkv, float* __restrict__ ctxp) {
    __shared__ float kb[64][40];
    __shared__ float vb[64][40];
    int seg = blockIdx.x;
    int bh  = blockIdx.y;
    int b = bh >> 3, h = bh & 7;
    int tid = threadIdx.x;
    int d  = tid >> 3;
    int e0 = (tid & 7) * 4;
    int lrow = tid >> 2, lcol = (tid & 3) * 8;
    float acc[4] = {0.f, 0.f, 0.f, 0.f};
    const size_t base = (size_t)b * N_ * 768 + h * 32;
    for (int n0 = seg * 512; n0 < seg * 512 + 512; n0 += 64) {
        size_t ra = base + (size_t)(n0 + lrow) * 768 + lcol;
        bf16x8 kv8 = *(const bf16x8*)(qkv + ra + 256);
        bf16x8 vv8 = *(const bf16x8*)(qkv + ra + 512);
#pragma unroll
        for (int j = 0; j < 8; ++j) {
            kb[lrow][lcol + j] = b2f(kv8[j]);
            vb[lrow][lcol + j] = b2f(vv8[j]);
        }
        __syncthreads();
#pragma unroll
        for (int nl = 0; nl < 64; ++nl) {
            float kv = fmaxf(kb[nl][d], 0.f);
#pragma unroll
            for (int j = 0; j < 4; ++j)
                acc[j] = fmaf(kv, vb[nl][e0 + j], acc[j]);
        }
        __syncthreads();
    }
    float* o = ctxp + ((size_t)seg * 64 + bh) * 1024 + d * 32 + e0;
#pragma unroll
    for (int j = 0; j < 4; ++j) o[j] = acc[j];
}

// ---------------------------------------------------------------------------
// attn_out with fused ctx reduction: cs = sum_seg ctxp[seg][bh]
__global__ void attn_out(const bf16_t* __restrict__ qkv, const float* __restrict__ ctxp,
                         bf16_t* __restrict__ img) {
    __shared__ float qb[64][33];
    __shared__ float cs[32][32];
    int n0 = blockIdx.x * 64;
    int bh = blockIdx.y;
    int b = bh >> 3, h = bh & 7;
    int tid = threadIdx.x;
    const float scale = 0.17677669529663687f;
    {
        f32x4 vv = (f32x4)0.f;
#pragma unroll
        for (int seg = 0; seg < 8; ++seg) {
            f32x4 t = ((const f32x4*)(ctxp + ((size_t)seg * 64 + bh) * 1024))[tid];
            vv = vv + t;
        }
        ((f32x4*)&cs[0][0])[tid] = vv;
    }
    const size_t base = (size_t)b * N_ * 768 + h * 32;
    int lrow = tid >> 2, lcol = (tid & 3) * 8;
    {
        bf16x8 q8 = *(const bf16x8*)(qkv + base + (size_t)(n0 + lrow) * 768 + lcol);
#pragma unroll
        for (int j = 0; j < 8; ++j)
            qb[lrow][lcol + j] = fmaxf(b2f(q8[j]), 0.f) * scale;
    }
    __syncthreads();
    int nl = tid & 63, ebase = tid >> 6;
    bf16_t* outp = img + ((size_t)b * C_ + h * 32) * N_ + n0 + nl;
#pragma unroll
    for (int p = 0; p < 8; ++p) {
        int e = ebase + p * 4;
        float s = 0.f;
#pragma unroll
        for (int dd = 0; dd < 32; ++dd)
            s = fmaf(qb[nl][dd], cs[dd][e], s);
        outp[(size_t)e * N_] = f2b(s);
    }
}

// ---------------------------------------------------------------------------
// Fused depthwise 3x3 conv + transpose: img [B,C,N] bf16 -> convT [B,N,C] bf16.
__global__ __launch_bounds__(256)
void dwconvT(const bf16_t* __restrict__ img, const float* __restrict__ w,
             const float* __restrict__ bias, bf16_t* __restrict__ outb) {
    __shared__ float spf[3][32][66];
    __shared__ float otile[64][33];
    int id = blockIdx.x;               // b*512 + y*8 + cg
    int cg = id & 7, y = (id >> 3) & 63, b = id >> 9;
    int tid = threadIdx.x;
    int c_l = tid >> 3, xg = tid & 7;
    int c = cg * 32 + c_l;
    const bf16_t* ip = img + (size_t)(b * C_ + c) * N_;
#pragma unroll
    for (int dy = 0; dy < 3; ++dy) {
        int yy = y + dy - 1;
        if (yy < 0 || yy > 63) {
#pragma unroll
            for (int j = 0; j < 8; ++j) spf[dy][c_l][xg * 8 + j] = 0.f;
        } else {
            bf16x8 v8 = *(const bf16x8*)(ip + yy * 64 + xg * 8);
#pragma unroll
            for (int j = 0; j < 8; ++j) spf[dy][c_l][xg * 8 + j] = b2f(v8[j]);
        }
    }
    float wv[9];
#pragma unroll
    for (int j = 0; j < 9; ++j) wv[j] = w[c * 9 + j];
    float bv = bias[c];
    __syncthreads();

    float o[8];
#pragma unroll
    for (int i = 0; i < 8; ++i) o[i] = bv;
#pragma unroll
    for (int dy = 0; dy < 3; ++dy)
#pragma unroll
        for (int dx = -1; dx <= 1; ++dx) {
            float wgt = wv[dy * 3 + dx + 1];
#pragma unroll
            for (int i = 0; i < 8; ++i) {
                int xx = xg * 8 + i + dx;
                float val = (xx < 0 || xx > 63) ? 0.f : spf[dy][c_l][xx];
                o[i] = fmaf(wgt, val, o[i]);
            }
        }
#pragma unroll
    for (int i = 0; i < 8; ++i) otile[xg * 8 + i][c_l] = o[i];
    __syncthreads();

    int x_o = tid >> 2, cq = tid & 3;
    bf16_t ob[8];
#pragma unroll
    for (int j = 0; j < 8; ++j) ob[j] = f2b(otile[x_o][cq * 8 + j]);
    *(bf16x8*)(outb + ((size_t)b * N_ + y * 64 + x_o) * 256 + cg * 32 + cq * 8) = *(bf16x8*)&ob[0];
}

// ---------------------------------------------------------------------------
extern "C" void kernel_launch(void* const* d_in, const int* in_sizes, int n_in,
                              void* d_out, int out_size, void* d_ws, size_t ws_size,
                              hipStream_t stream) {
    const float* x     = (const float*)d_in[0];
    const float* Wqkv  = (const float*)d_in[1];
    const float* bqkv  = (const float*)d_in[2];
    const float* dw_w  = (const float*)d_in[3];
    const float* dw_b  = (const float*)d_in[4];
    const float* Wproj = (const float*)d_in[5];
    const float* bproj = (const float*)d_in[6];
    const float* bn1_g = (const float*)d_in[7];
    const float* bn1_b = (const float*)d_in[8];
    const float* bn1_m = (const float*)d_in[9];
    const float* bn1_v = (const float*)d_in[10];
    const float* alpha1= (const float*)d_in[11];
    const float* Wfc1  = (const float*)d_in[12];
    const float* bfc1  = (const float*)d_in[13];
    const float* Wfc2  = (const float*)d_in[14];
    const float* bfc2  = (const float*)d_in[15];
    const float* bn2_g = (const float*)d_in[16];
    const float* bn2_b = (const float*)d_in[17];
    const float* bn2_m = (const float*)d_in[18];
    const float* bn2_v = (const float*)d_in[19];
    const float* alpha2= (const float*)d_in[20];
    float* out = (float*)d_out;

    char* ws = (char*)d_ws;
    bf16_t* t_b2    = (bf16_t*)(ws);
    bf16_t* WqkvT   = (bf16_t*)(ws + 16777216);
    bf16_t* WprojT  = (bf16_t*)(ws + 17170432);
    bf16_t* Wfc1T   = (bf16_t*)(ws + 17301504);
    bf16_t* Wfc2T   = (bf16_t*)(ws + 18350080);
    float*  ctxp    = (float*)(ws + 19398656);
    bf16_t* t_b     = (bf16_t*)(ws + 21757952);
    bf16_t* qkv_b   = (bf16_t*)(ws + 38535168);
    bf16_t* img_b   = (bf16_t*)(ws + 88866816);
    bf16_t* convT_b = (bf16_t*)(ws + 122421248);

    // ph1: merged prep (transpose x + all 4 weight casts)
    prep<<<9472, dim3(32, 8), 0, stream>>>(x, t_b, Wqkv, WqkvT, Wproj, WprojT,
                                           Wfc1, Wfc1T, Wfc2, Wfc2T);

    // ph2: qkv_b = bf16(t @ Wqkv + bqkv)
    gemm_swp<4><<<dim3(768 / 128, M_ / 128), 256, 0, stream>>>(
        WqkvT, t_b, bqkv, qkv_b, M_, 768, C_,
        nullptr, nullptr, nullptr, nullptr, nullptr, nullptr);

    // ph3: ctx partials (reduction folded into attn_out)
    ctx_partial<<<dim3(8, B_ * NH_), 256, 0, stream>>>(qkv_b, ctxp);

    // ph4: img_b = (relu(q)*scale) @ ctx   [B,C,N] bf16
    attn_out<<<dim3(N_ / 64, B_ * NH_), 256, 0, stream>>>(qkv_b, ctxp, img_b);

    // ph5: fused depthwise conv + transpose -> convT_b [B,N,C]
    dwconvT<<<B_ * 64 * 8, 256, 0, stream>>>(img_b, dw_w, dw_b, convT_b);

    // ph6: t_b2 = repbn1(t_b + convT @ Wproj + bproj)
    gemm_swp<1><<<dim3(C_ / 128, M_ / 128), 256, 0, stream>>>(
        WprojT, convT_b, bproj, t_b2, M_, C_, C_,
        t_b, bn1_g, bn1_b, bn1_m, bn1_v, alpha1);

    // ph7: fused FFN v4 (verified best)
    ffn_fused<<<M_ / 64, 512, 0, stream>>>(
        t_b2, Wfc1T, Wfc2T, bfc1, bfc2,
        bn2_g, bn2_b, bn2_m, bn2_v, alpha2, out);
}